// Round 7
// baseline (459.956 us; speedup 1.0000x reference)
//
#include <hip/hip_runtime.h>

// Decoder_33208687133135 — fused Koopman decoder, MI355X (gfx950).
// Diagonal-only -> layer4 is a per-row dot. ~292 GFLOP, f16 MFMA
// (absmax 0.0625 vs thr 0.2425, stable R1-R6).
//
// R6 post-mortem: corrected model — MFMA floor is 141 us (not 35; R4 math
// error) and MfmaUtil 38.6% x 363 us == 140 us: MFMA pipe already at floor.
// Weight L2 stream (2048 WG x 2.36 MB = 4.8 GB = 140 us) is a co-equal
// floor. Spill (WRITE 70-82 MB) persisted across R4-R6: 4 waves/SIMD with
// 64 acc AGPRs leaves too few arch VGPRs — decomposition wrong.
// R7: M=128 (2 batches/WG, grid 1024) + mfma_f32_32x32x16_f16 @ 2 waves/SIMD:
//   - weight L2 traffic halves -> 70 us floor (under MFMA floor)
//   - 32x32 rate 2382 TF -> MFMA floor 123 us, half the issue slots
//   - 256 unified regs/lane: acc 128 AGPR + ~60 arch -> no spill possible
//   - LDS 145 KB (ZA 16 + HA 128 + red 1), 1 WG/CU.

typedef _Float16 f16;
typedef _Float16 f16x8 __attribute__((ext_vector_type(8)));
typedef float f32x16 __attribute__((ext_vector_type(16)));

#define WPACK_PER_NET 589824
#define OFF_W1 0
#define OFF_W2 32768
#define OFF_W3 294912
#define OFF_W4T 557056
#define WPACK_BYTES (2u * WPACK_PER_NET * sizeof(f16))  // 2.36 MB

// Barrier with LDS-visibility only (no vmcnt drain): in-flight global
// weight prefetches survive the barrier.
__device__ __forceinline__ void lds_barrier() {
  asm volatile("s_waitcnt lgkmcnt(0)\n\ts_barrier" ::: "memory");
}

// ---------------- pack: fp32 -> f16, 32x32x16 B-frag entries -------------
// Layer block f16 index: f = s*8192 + w*1024 + nt*512 + ln*8 + j
// holding B[k][n]: n = w*64 + nt*32 + (ln&31), k = s*16 + (ln>>5)*8 + j.
// Decoder: wave w, slice s: byte base = blk + s*16384 + w*2048 + lane*16,
// two 16B loads at imm offsets {0, 1024}. W4T: [i][k] transpose.
__global__ void pack_weights(const float* __restrict__ sW1, const float* __restrict__ sW2,
                             const float* __restrict__ sW3, const float* __restrict__ sW4,
                             const float* __restrict__ tW1, const float* __restrict__ tW2,
                             const float* __restrict__ tW3, const float* __restrict__ tW4,
                             f16* __restrict__ dst) {
  int idx = blockIdx.x * 256 + threadIdx.x;  // 4608*256 == 2*WPACK_PER_NET
  int net = idx >= WPACK_PER_NET;
  int f = idx - net * WPACK_PER_NET;
  const float* W;
  int base;
  if (f < OFF_W2) {
    W = net ? tW1 : sW1; base = OFF_W1;
  } else if (f < OFF_W3) {
    W = net ? tW2 : sW2; base = OFF_W2;
  } else if (f < OFF_W4T) {
    W = net ? tW3 : sW3; base = OFF_W3;
  } else {
    int f4 = f - OFF_W4T;
    dst[idx] = (f16)((net ? tW4 : sW4)[(f4 & 511) * 64 + (f4 >> 9)]);
    return;
  }
  int fl = f - base;
  int j = fl & 7, ln = (fl >> 3) & 63, nt = (fl >> 9) & 1, w = (fl >> 10) & 7,
      s = fl >> 13;
  dst[idx] = (f16)W[(s * 16 + (ln >> 5) * 8 + j) * 512 + w * 64 + nt * 32 + (ln & 31)];
}

// A-frag order (32x32x16) for element (m,k), M=128 tile:
// slice=k>>4, chunk=m>>5, lane=(m&31)+((k>>3)&1)*32, j=k&7.
__device__ __forceinline__ int aidx2(int m, int k) {
  return (((k >> 4) * 4 + (m >> 5)) * 64 + (m & 31) + ((k >> 3) & 1) * 32) * 8 + (k & 7);
}

// tanh(x) = 1 - 2/(exp(2x)+1); 6 VALU inst, correct saturation.
__device__ __forceinline__ float fast_tanh(float x) {
  float e = __expf(x + x);
  return fmaf(-2.0f, __builtin_amdgcn_rcpf(e + 1.0f), 1.0f);
}

// One MLP layer: Hout(128xN=512) = tanh(Asrc(128xK) @ W(Kx512) + bias).
// Wave w owns cols [64w,64w+64) as two 32-col tiles. NS2 = K/16 slices.
template <int NS2>
__device__ __forceinline__ void mlp_layer(const char* __restrict__ wlb,
                                          const float* __restrict__ bias,
                                          const f16* Asrc, f16* Hout,
                                          int wave, int lane, int sbase) {
  f32x16 acc[4][2];
  {
    float bv0 = bias[wave * 64 + (lane & 31)];
    float bv1 = bias[wave * 64 + 32 + (lane & 31)];
#pragma unroll
    for (int mt = 0; mt < 4; mt++)
#pragma unroll
      for (int r = 0; r < 16; r++) {
        acc[mt][0][r] = bv0;
        acc[mt][1][r] = bv1;
      }
  }
  f16x8 bb[2][2];
  bb[0][0] = *(const f16x8*)(wlb);
  bb[0][1] = *(const f16x8*)(wlb + 1024);
#pragma unroll
  for (int s = 0; s < NS2; s++) {
    if (s + 1 < NS2) {
      const char* q = wlb + (s + 1) * 16384;
      bb[(s + 1) & 1][0] = *(const f16x8*)(q);
      bb[(s + 1) & 1][1] = *(const f16x8*)(q + 1024);
    }
    const f16* ab = Asrc + s * 2048 + lane * 8;
#pragma unroll
    for (int mt = 0; mt < 4; mt++) {
      f16x8 a = *(const f16x8*)(ab + mt * 512);
      acc[mt][0] = __builtin_amdgcn_mfma_f32_32x32x16_f16(a, bb[s & 1][0],
                                                          acc[mt][0], 0, 0, 0);
      acc[mt][1] = __builtin_amdgcn_mfma_f32_32x32x16_f16(a, bb[s & 1][1],
                                                          acc[mt][1], 0, 0, 0);
    }
  }
  lds_barrier();  // all waves done reading Asrc (may alias Hout)
  // C/D (m74/m101): col = lane&31, row = (reg&3) + 8*(reg>>2) + 4*(lane>>5).
  // Scatter into A-frag order = sbase(lane) + const(mt,nt,reg):
  //   const = nt*4096 + mt*512 + (reg>>2)*64 + (reg&3)*8   [spot-checked]
  f16* hb = Hout + sbase;
#pragma unroll
  for (int mt = 0; mt < 4; mt++)
#pragma unroll
    for (int nt = 0; nt < 2; nt++)
#pragma unroll
      for (int r = 0; r < 16; r++)
        hb[nt * 4096 + mt * 512 + (r >> 2) * 64 + (r & 3) * 8] =
            (f16)fast_tanh(acc[mt][nt][r]);
  lds_barrier();
}

__global__ __launch_bounds__(512, 2) void decoder_main(
    const float* __restrict__ x, const float* __restrict__ koop,
    const f16* __restrict__ wpack,
    const float* __restrict__ sb1, const float* __restrict__ sb2,
    const float* __restrict__ sb3, const float* __restrict__ sb4,
    const float* __restrict__ tb1, const float* __restrict__ tb2,
    const float* __restrict__ tb3, const float* __restrict__ tb4,
    float* __restrict__ out) {
  __shared__ __align__(16) f16 ZA[8192];   // z tile 128x64, A-frag (16 KB)
  __shared__ __align__(16) f16 HA[65536];  // activations 128x512 (128 KB)
  __shared__ float redBuf[2][128];
  // ~145.4 KB -> 1 WG/CU (2 waves/SIMD, 256 unified regs/lane)

  const int b = blockIdx.x;            // handles batches 2b, 2b+1
  const int t = threadIdx.x;
  const int wave = t >> 6, lane = t & 63;
  const int ln5 = lane & 31, q5 = lane >> 5;
  // sbase for the C->A scatter [derived + spot-checked in R7 notes]:
  const int sbase = wave * 8192 + (ln5 >> 4) * 2048 + ((ln5 >> 3) & 1) * 256 +
                    q5 * 32 + (ln5 & 7);
  // Wave's byte base within any packed layer block.
  const char* wbb = (const char*)wpack + wave * 2048 + lane * 16;

  // Stage z for both batches: koop[(2b+bi)][l][d] -> ZA[m=bi*64+d][k=l].
  const float* kb = koop + (size_t)b * 8192;
#pragma unroll
  for (int i = 0; i < 16; i++) {
    int flat = t + 512 * i;  // coalesced fp32 read
    int bi = flat >> 12, rem = flat & 4095;
    ZA[aidx2(bi * 64 + (rem & 63), rem >> 6)] = (f16)kb[flat];
  }
  lds_barrier();

  for (int net = 0; net < 2; net++) {
    const size_t nb = (size_t)net * (WPACK_PER_NET * 2);
    const float* b1 = net ? tb1 : sb1;
    const float* b2 = net ? tb2 : sb2;
    const float* b3 = net ? tb3 : sb3;
    const float* b4 = net ? tb4 : sb4;
    mlp_layer<4>(wbb + nb + OFF_W1 * 2, b1, ZA, HA, wave, lane, sbase);
    mlp_layer<32>(wbb + nb + OFF_W2 * 2, b2, HA, HA, wave, lane, sbase);
    mlp_layer<32>(wbb + nb + OFF_W3 * 2, b3, HA, HA, wave, lane, sbase);

    // Diagonal epilogue: rows m=0..127, ds[m] = H3[m,:] . W4T[m&63,:] + b4.
    const f16* w4t = wpack + net * WPACK_PER_NET + OFF_W4T;
    int i2 = t >> 2, sub = t & 3;  // 4 threads per row, 128 k each
    float p = 0.f;
#pragma unroll
    for (int qq = 0; qq < 16; qq++) {
      int k0 = sub * 128 + qq * 8;
      f16x8 hv = *(const f16x8*)&HA[aidx2(i2, k0)];
      f16x8 wv = *(const f16x8*)&w4t[(i2 & 63) * 512 + k0];
#pragma unroll
      for (int j = 0; j < 8; j++) p += (float)hv[j] * (float)wv[j];
    }
    p += __shfl_down(p, 2, 4);
    p += __shfl_down(p, 1, 4);
    if (sub == 0) redBuf[net][i2] = p + b4[i2 & 63];
    lds_barrier();
  }

  if (t < 128) {
    out[b * 128 + t] = (x[b * 128 + t] - redBuf[1][t]) * __expf(-redBuf[0][t]);
  }
}

// ---------------- DIRECT fallback (no workspace) — R6 code ---------------
typedef float f32x4 __attribute__((ext_vector_type(4)));

__device__ __forceinline__ int aidx(int m, int k) {
  return (((k >> 5) * 4 + (m >> 4)) * 64 + (m & 15) + ((k >> 3) & 3) * 16) * 8 + (k & 7);
}

__device__ __forceinline__ void load_b_direct(const float* __restrict__ Wraw,
                                              int kk, int wave, int lane,
                                              f16x8* bdst) {
  int n0 = wave * 64 + (lane & 15);
  int kb = kk * 32 + (lane >> 4) * 8;
#pragma unroll
  for (int nt = 0; nt < 4; nt++) {
    f16x8 v;
#pragma unroll
    for (int j = 0; j < 8; j++) v[j] = (f16)Wraw[(kb + j) * 512 + n0 + nt * 16];
    bdst[nt] = v;
  }
}

template <int NS>
__device__ __forceinline__ void mlp_layer_direct(
    const float* __restrict__ Wraw, const float* __restrict__ bias,
    const f16* Asrc, f16* Hout, int wave, int lane, int sbase) {
  f32x4 acc[4][4];
#pragma unroll
  for (int nt = 0; nt < 4; nt++) {
    float bv = bias[wave * 64 + nt * 16 + (lane & 15)];
#pragma unroll
    for (int mt = 0; mt < 4; mt++) acc[mt][nt] = f32x4{bv, bv, bv, bv};
  }
  f16x8 bb[2][4];
  load_b_direct(Wraw, 0, wave, lane, bb[0]);
#pragma unroll
  for (int kk = 0; kk < NS; kk++) {
    if (kk + 1 < NS) load_b_direct(Wraw, kk + 1, wave, lane, bb[(kk + 1) & 1]);
    const f16* ab = Asrc + kk * 2048 + lane * 8;
#pragma unroll
    for (int mt = 0; mt < 4; mt++) {
      f16x8 a = *(const f16x8*)(ab + mt * 512);
#pragma unroll
      for (int nt = 0; nt < 4; nt++)
        acc[mt][nt] = __builtin_amdgcn_mfma_f32_16x16x32_f16(a, bb[kk & 1][nt],
                                                             acc[mt][nt], 0, 0, 0);
    }
  }
  __syncthreads();
  f16* hb = Hout + sbase;
#pragma unroll
  for (int mt = 0; mt < 4; mt++)
#pragma unroll
    for (int nt = 0; nt < 4; nt++)
#pragma unroll
      for (int r = 0; r < 4; r++)
        hb[(nt >> 1) * 2048 + mt * 512 + (nt & 1) * 256 + r * 8] =
            (f16)fast_tanh(acc[mt][nt][r]);
  __syncthreads();
}

__global__ __launch_bounds__(512, 4) void decoder_direct(
    const float* __restrict__ x, const float* __restrict__ koop,
    const float* __restrict__ sW1, const float* __restrict__ sW2,
    const float* __restrict__ sW3, const float* __restrict__ sW4,
    const float* __restrict__ tW1, const float* __restrict__ tW2,
    const float* __restrict__ tW3, const float* __restrict__ tW4,
    const float* __restrict__ sb1, const float* __restrict__ sb2,
    const float* __restrict__ sb3, const float* __restrict__ sb4,
    const float* __restrict__ tb1, const float* __restrict__ tb2,
    const float* __restrict__ tb3, const float* __restrict__ tb4,
    float* __restrict__ out) {
  __shared__ __align__(16) f16 ZA[4096];
  __shared__ __align__(16) f16 HA[32768];
  __shared__ float redBuf[2][64];
  const int b = blockIdx.x;
  const int t = threadIdx.x;
  const int wave = t >> 6, lane = t & 63;
  const int sbase =
      wave * 4096 + (lane >> 4) * 32 + ((lane & 15) >> 3) * 128 + (lane & 7);
  const float* kb = koop + b * 4096;
#pragma unroll
  for (int i = 0; i < 8; i++) {
    int flat = t + 512 * i;
    ZA[aidx(flat & 63, flat >> 6)] = (f16)kb[flat];
  }
  __syncthreads();
  for (int net = 0; net < 2; net++) {
    const float* W1 = net ? tW1 : sW1;
    const float* W2 = net ? tW2 : sW2;
    const float* W3 = net ? tW3 : sW3;
    const float* W4 = net ? tW4 : sW4;
    const float* b1 = net ? tb1 : sb1;
    const float* b2 = net ? tb2 : sb2;
    const float* b3 = net ? tb3 : sb3;
    const float* b4 = net ? tb4 : sb4;
    mlp_layer_direct<2>(W1, b1, ZA, HA, wave, lane, sbase);
    mlp_layer_direct<16>(W2, b2, HA, HA, wave, lane, sbase);
    mlp_layer_direct<16>(W3, b3, HA, HA, wave, lane, sbase);
    int i = t >> 3, sub = t & 7;
    float p = 0.f;
#pragma unroll
    for (int qq = 0; qq < 8; qq++) {
      int k0 = sub * 64 + qq * 8;
      f16x8 hv = *(const f16x8*)&HA[aidx(i, k0)];
#pragma unroll
      for (int j = 0; j < 8; j++) p += (float)hv[j] * W4[(k0 + j) * 64 + i];
    }
    p += __shfl_down(p, 4, 8);
    p += __shfl_down(p, 2, 8);
    p += __shfl_down(p, 1, 8);
    if (sub == 0) redBuf[net][i] = p + b4[i];
    __syncthreads();
  }
  if (t < 64) {
    out[b * 64 + t] = (x[b * 64 + t] - redBuf[1][t]) * __expf(-redBuf[0][t]);
  }
}

extern "C" void kernel_launch(void* const* d_in, const int* in_sizes, int n_in,
                              void* d_out, int out_size, void* d_ws, size_t ws_size,
                              hipStream_t stream) {
  const float* x    = (const float*)d_in[0];
  const float* koop = (const float*)d_in[1];
  const float* sW1 = (const float*)d_in[2];  const float* sb1 = (const float*)d_in[3];
  const float* sW2 = (const float*)d_in[4];  const float* sb2 = (const float*)d_in[5];
  const float* sW3 = (const float*)d_in[6];  const float* sb3 = (const float*)d_in[7];
  const float* sW4 = (const float*)d_in[8];  const float* sb4 = (const float*)d_in[9];
  const float* tW1 = (const float*)d_in[10]; const float* tb1 = (const float*)d_in[11];
  const float* tW2 = (const float*)d_in[12]; const float* tb2 = (const float*)d_in[13];
  const float* tW3 = (const float*)d_in[14]; const float* tb3 = (const float*)d_in[15];
  const float* tW4 = (const float*)d_in[16]; const float* tb4 = (const float*)d_in[17];
  float* out = (float*)d_out;

  // Launch-invariant branch (ws_size constant across calls) -> graph-safe.
  // NEVER write past ws_size (R1 lesson).
  if (ws_size >= (size_t)WPACK_BYTES) {
    f16* wpack = (f16*)d_ws;
    pack_weights<<<4608, 256, 0, stream>>>(sW1, sW2, sW3, sW4, tW1, tW2, tW3, tW4,
                                           wpack);
    decoder_main<<<1024, 512, 0, stream>>>(x, koop, wpack,
                                           sb1, sb2, sb3, sb4,
                                           tb1, tb2, tb3, tb4, out);
  } else {
    decoder_direct<<<2048, 512, 0, stream>>>(
        x, koop, sW1, sW2, sW3, sW4, tW1, tW2, tW3, tW4,
        sb1, sb2, sb3, sb4, tb1, tb2, tb3, tb4, out);
  }
}

// Round 8
// 444.702 us; speedup vs baseline: 1.0343x; 1.0343x over previous
//
#include <hip/hip_runtime.h>

// Decoder_33208687133135 — fused Koopman decoder, MI355X (gfx950).
// Diagonal-only -> layer4 is a per-row dot. ~292 GFLOP, f16 MFMA
// (absmax 0.0625 vs thr 0.2425, stable R1-R7).
//
// R7 post-mortem: M=128 / 32x32x16 / 2 waves/SIMD KILLED the spill
// (WRITE 70MB->0.5MB, VGPR 128+128) and FETCH=26MB=pure inputs, but 429 us:
// SQ_LDS_BANK_CONFLICT 4.17e7 (8-way on the C->A scatter, ~16% of cycles)
// + ~46% exposed ds_read->MFMA latency at only 2 waves/SIMD.
// R8: (1) XOR swizzle idx^=bit8<<3^bit11<<4 on HA/ZA -> all 64 lanes hit
// distinct bank residues on scatter stores (2/bank = free), a-frag 16B reads
// stay block-contiguous (read side: lane ^ (q5 + 2*(s&1)));
// (2) register double-buffer of a-frags (+b) — prefetch slice s+1 during
// slice s's 8 MFMAs. Arch regs ~80 < 128: no spill possible.

typedef _Float16 f16;
typedef _Float16 f16x8 __attribute__((ext_vector_type(8)));
typedef float f32x16 __attribute__((ext_vector_type(16)));

#define WPACK_PER_NET 589824
#define OFF_W1 0
#define OFF_W2 32768
#define OFF_W3 294912
#define OFF_W4T 557056
#define WPACK_BYTES (2u * WPACK_PER_NET * sizeof(f16))  // 2.36 MB

// Barrier with LDS-visibility only (no vmcnt drain): in-flight global
// weight prefetches survive the barrier.
__device__ __forceinline__ void lds_barrier() {
  asm volatile("s_waitcnt lgkmcnt(0)\n\ts_barrier" ::: "memory");
}

// ---------------- pack: fp32 -> f16, 32x32x16 B-frag entries -------------
// Layer block f16 index: f = s*8192 + w*1024 + nt*512 + ln*8 + j
// holding B[k][n]: n = w*64 + nt*32 + (ln&31), k = s*16 + (ln>>5)*8 + j.
// Decoder: wave w, slice s: byte base = blk + s*16384 + w*2048 + lane*16,
// two 16B loads at imm offsets {0, 1024}. W4T: [i][k] transpose.
__global__ void pack_weights(const float* __restrict__ sW1, const float* __restrict__ sW2,
                             const float* __restrict__ sW3, const float* __restrict__ sW4,
                             const float* __restrict__ tW1, const float* __restrict__ tW2,
                             const float* __restrict__ tW3, const float* __restrict__ tW4,
                             f16* __restrict__ dst) {
  int idx = blockIdx.x * 256 + threadIdx.x;  // 4608*256 == 2*WPACK_PER_NET
  int net = idx >= WPACK_PER_NET;
  int f = idx - net * WPACK_PER_NET;
  const float* W;
  int base;
  if (f < OFF_W2) {
    W = net ? tW1 : sW1; base = OFF_W1;
  } else if (f < OFF_W3) {
    W = net ? tW2 : sW2; base = OFF_W2;
  } else if (f < OFF_W4T) {
    W = net ? tW3 : sW3; base = OFF_W3;
  } else {
    int f4 = f - OFF_W4T;
    dst[idx] = (f16)((net ? tW4 : sW4)[(f4 & 511) * 64 + (f4 >> 9)]);
    return;
  }
  int fl = f - base;
  int j = fl & 7, ln = (fl >> 3) & 63, nt = (fl >> 9) & 1, w = (fl >> 10) & 7,
      s = fl >> 13;
  dst[idx] = (f16)W[(s * 16 + (ln >> 5) * 8 + j) * 512 + w * 64 + nt * 32 + (ln & 31)];
}

// A-frag order (32x32x16) for element (m,k), M=128 tile (unswizzled):
// idx = ((k>>4)*4 + (m>>5))*512 + ((m&31) + ((k>>3)&1)*32)*8 + (k&7).
__device__ __forceinline__ int aidx2(int m, int k) {
  return (((k >> 4) * 4 + (m >> 5)) * 64 + (m & 31) + ((k >> 3) & 1) * 32) * 8 + (k & 7);
}

// Bank swizzle: XOR bits 3-4 with bits 8,11. Scatter stores become
// conflict-free (64 distinct residues mod 64); 16B blocks stay contiguous
// (bits 8,11 constant within a block).
__device__ __forceinline__ int swz(int idx) {
  return idx ^ (((idx >> 8) & 1) << 3) ^ (((idx >> 11) & 1) << 4);
}

// tanh(x) = 1 - 2/(exp(2x)+1); 6 VALU inst, correct saturation.
__device__ __forceinline__ float fast_tanh(float x) {
  float e = __expf(x + x);
  return fmaf(-2.0f, __builtin_amdgcn_rcpf(e + 1.0f), 1.0f);
}

// One MLP layer: Hout(128x512) = tanh(Asrc(128xK) @ W(Kx512) + bias).
// Wave w owns cols [64w,64w+64) as two 32-col tiles. NS2 = K/16 slices.
// Register double-buffer of both a-frags (LDS) and b-frags (global).
// rl0/rl1: swizzled lane byte-offsets for even/odd slices; sx = (lane>>3)&3.
template <int NS2>
__device__ __forceinline__ void mlp_layer(const char* __restrict__ wlb,
                                          const float* __restrict__ bias,
                                          const f16* Asrc, f16* Hout,
                                          int wave, int lane, int sbase,
                                          int sx, int rl0, int rl1) {
  f32x16 acc[4][2];
  {
    float bv0 = bias[wave * 64 + (lane & 31)];
    float bv1 = bias[wave * 64 + 32 + (lane & 31)];
#pragma unroll
    for (int mt = 0; mt < 4; mt++)
#pragma unroll
      for (int r = 0; r < 16; r++) {
        acc[mt][0][r] = bv0;
        acc[mt][1][r] = bv1;
      }
  }
  f16x8 bb[2][2], aa[2][4];
  bb[0][0] = *(const f16x8*)(wlb);
  bb[0][1] = *(const f16x8*)(wlb + 1024);
  {
    const f16* a0 = Asrc + rl0;  // slice 0 (even): lane ^ q5
#pragma unroll
    for (int mt = 0; mt < 4; mt++) aa[0][mt] = *(const f16x8*)(a0 + mt * 512);
  }
#pragma unroll
  for (int s = 0; s < NS2; s++) {
    if (s + 1 < NS2) {
      const char* q = wlb + (s + 1) * 16384;
      bb[(s + 1) & 1][0] = *(const f16x8*)(q);
      bb[(s + 1) & 1][1] = *(const f16x8*)(q + 1024);
      const f16* an = Asrc + (s + 1) * 2048 + (((s + 1) & 1) ? rl1 : rl0);
#pragma unroll
      for (int mt = 0; mt < 4; mt++)
        aa[(s + 1) & 1][mt] = *(const f16x8*)(an + mt * 512);
    }
#pragma unroll
    for (int mt = 0; mt < 4; mt++) {
      acc[mt][0] = __builtin_amdgcn_mfma_f32_32x32x16_f16(aa[s & 1][mt], bb[s & 1][0],
                                                          acc[mt][0], 0, 0, 0);
      acc[mt][1] = __builtin_amdgcn_mfma_f32_32x32x16_f16(aa[s & 1][mt], bb[s & 1][1],
                                                          acc[mt][1], 0, 0, 0);
    }
  }
  lds_barrier();  // all waves done reading Asrc (may alias Hout)
  // C/D (m74/m101): col = lane&31, row = (r&3) + 8*(r>>2) + 4*(lane>>5).
  // Swizzled scatter: idx = sbase + nt*4096 + mt*512 + (r>>2)*64
  //                   + ((r&3)^sx)*8  -> 4 base ptrs indexed by r&3,
  // immediates for the rest; conflict-free (2 lanes/bank).
  f16* hx[4];
#pragma unroll
  for (int v = 0; v < 4; v++) hx[v] = Hout + sbase + ((v ^ sx) << 3);
#pragma unroll
  for (int mt = 0; mt < 4; mt++)
#pragma unroll
    for (int nt = 0; nt < 2; nt++)
#pragma unroll
      for (int r = 0; r < 16; r++)
        hx[r & 3][nt * 4096 + mt * 512 + (r >> 2) * 64] =
            (f16)fast_tanh(acc[mt][nt][r]);
  lds_barrier();
}

__global__ __launch_bounds__(512, 2) void decoder_main(
    const float* __restrict__ x, const float* __restrict__ koop,
    const f16* __restrict__ wpack,
    const float* __restrict__ sb1, const float* __restrict__ sb2,
    const float* __restrict__ sb3, const float* __restrict__ sb4,
    const float* __restrict__ tb1, const float* __restrict__ tb2,
    const float* __restrict__ tb3, const float* __restrict__ tb4,
    float* __restrict__ out) {
  __shared__ __align__(16) f16 ZA[8192];   // z tile 128x64, A-frag (16 KB)
  __shared__ __align__(16) f16 HA[65536];  // activations 128x512 (128 KB)
  __shared__ float redBuf[2][128];
  // ~145.4 KB -> 1 WG/CU (2 waves/SIMD, 256 unified regs/lane)

  const int b = blockIdx.x;            // handles batches 2b, 2b+1
  const int t = threadIdx.x;
  const int wave = t >> 6, lane = t & 63;
  const int ln5 = lane & 31, q5 = lane >> 5;
  const int sx = (lane >> 3) & 3;              // scatter swizzle bits
  const int rl0 = (lane ^ q5) * 8;             // even-slice a-read offset
  const int rl1 = rl0 ^ 16;                    // odd-slice (bit11 toggle)
  // sbase: lane part of the C->A scatter (bits 0-2,5,8,11,13+; no 3-4).
  const int sbase = wave * 8192 + (ln5 >> 4) * 2048 + ((ln5 >> 3) & 1) * 256 +
                    q5 * 32 + (ln5 & 7);
  // Wave's byte base within any packed layer block.
  const char* wbb = (const char*)wpack + wave * 2048 + lane * 16;

  // Stage z for both batches: koop[(2b+bi)][l][d] -> ZA[m=bi*64+d][k=l].
  const float* kb = koop + (size_t)b * 8192;
#pragma unroll
  for (int i = 0; i < 16; i++) {
    int flat = t + 512 * i;  // coalesced fp32 read
    int bi = flat >> 12, rem = flat & 4095;
    ZA[swz(aidx2(bi * 64 + (rem & 63), rem >> 6))] = (f16)kb[flat];
  }
  lds_barrier();

  for (int net = 0; net < 2; net++) {
    const size_t nb = (size_t)net * (WPACK_PER_NET * 2);
    const float* b1 = net ? tb1 : sb1;
    const float* b2 = net ? tb2 : sb2;
    const float* b3 = net ? tb3 : sb3;
    const float* b4 = net ? tb4 : sb4;
    mlp_layer<4>(wbb + nb + OFF_W1 * 2, b1, ZA, HA, wave, lane, sbase, sx, rl0, rl1);
    mlp_layer<32>(wbb + nb + OFF_W2 * 2, b2, HA, HA, wave, lane, sbase, sx, rl0, rl1);
    mlp_layer<32>(wbb + nb + OFF_W3 * 2, b3, HA, HA, wave, lane, sbase, sx, rl0, rl1);

    // Diagonal epilogue: rows m=0..127, ds[m] = H3[m,:] . W4T[m&63,:] + b4.
    const f16* w4t = wpack + net * WPACK_PER_NET + OFF_W4T;
    int i2 = t >> 2, sub = t & 3;  // 4 threads per row, 128 k each
    float p = 0.f;
#pragma unroll
    for (int qq = 0; qq < 16; qq++) {
      int k0 = sub * 128 + qq * 8;
      f16x8 hv = *(const f16x8*)&HA[swz(aidx2(i2, k0))];
      f16x8 wv = *(const f16x8*)&w4t[(i2 & 63) * 512 + k0];
#pragma unroll
      for (int j = 0; j < 8; j++) p += (float)hv[j] * (float)wv[j];
    }
    p += __shfl_down(p, 2, 4);
    p += __shfl_down(p, 1, 4);
    if (sub == 0) redBuf[net][i2] = p + b4[i2 & 63];
    lds_barrier();
  }

  if (t < 128) {
    out[b * 128 + t] = (x[b * 128 + t] - redBuf[1][t]) * __expf(-redBuf[0][t]);
  }
}

// ---------------- DIRECT fallback (no workspace) — R6 code ---------------
typedef float f32x4 __attribute__((ext_vector_type(4)));

__device__ __forceinline__ int aidx(int m, int k) {
  return (((k >> 5) * 4 + (m >> 4)) * 64 + (m & 15) + ((k >> 3) & 3) * 16) * 8 + (k & 7);
}

__device__ __forceinline__ void load_b_direct(const float* __restrict__ Wraw,
                                              int kk, int wave, int lane,
                                              f16x8* bdst) {
  int n0 = wave * 64 + (lane & 15);
  int kb = kk * 32 + (lane >> 4) * 8;
#pragma unroll
  for (int nt = 0; nt < 4; nt++) {
    f16x8 v;
#pragma unroll
    for (int j = 0; j < 8; j++) v[j] = (f16)Wraw[(kb + j) * 512 + n0 + nt * 16];
    bdst[nt] = v;
  }
}

template <int NS>
__device__ __forceinline__ void mlp_layer_direct(
    const float* __restrict__ Wraw, const float* __restrict__ bias,
    const f16* Asrc, f16* Hout, int wave, int lane, int sbase) {
  f32x4 acc[4][4];
#pragma unroll
  for (int nt = 0; nt < 4; nt++) {
    float bv = bias[wave * 64 + nt * 16 + (lane & 15)];
#pragma unroll
    for (int mt = 0; mt < 4; mt++) acc[mt][nt] = f32x4{bv, bv, bv, bv};
  }
  f16x8 bb[2][4];
  load_b_direct(Wraw, 0, wave, lane, bb[0]);
#pragma unroll
  for (int kk = 0; kk < NS; kk++) {
    if (kk + 1 < NS) load_b_direct(Wraw, kk + 1, wave, lane, bb[(kk + 1) & 1]);
    const f16* ab = Asrc + kk * 2048 + lane * 8;
#pragma unroll
    for (int mt = 0; mt < 4; mt++) {
      f16x8 a = *(const f16x8*)(ab + mt * 512);
#pragma unroll
      for (int nt = 0; nt < 4; nt++)
        acc[mt][nt] = __builtin_amdgcn_mfma_f32_16x16x32_f16(a, bb[kk & 1][nt],
                                                             acc[mt][nt], 0, 0, 0);
    }
  }
  __syncthreads();
  f16* hb = Hout + sbase;
#pragma unroll
  for (int mt = 0; mt < 4; mt++)
#pragma unroll
    for (int nt = 0; nt < 4; nt++)
#pragma unroll
      for (int r = 0; r < 4; r++)
        hb[(nt >> 1) * 2048 + mt * 512 + (nt & 1) * 256 + r * 8] =
            (f16)fast_tanh(acc[mt][nt][r]);
  __syncthreads();
}

__global__ __launch_bounds__(512, 4) void decoder_direct(
    const float* __restrict__ x, const float* __restrict__ koop,
    const float* __restrict__ sW1, const float* __restrict__ sW2,
    const float* __restrict__ sW3, const float* __restrict__ sW4,
    const float* __restrict__ tW1, const float* __restrict__ tW2,
    const float* __restrict__ tW3, const float* __restrict__ tW4,
    const float* __restrict__ sb1, const float* __restrict__ sb2,
    const float* __restrict__ sb3, const float* __restrict__ sb4,
    const float* __restrict__ tb1, const float* __restrict__ tb2,
    const float* __restrict__ tb3, const float* __restrict__ tb4,
    float* __restrict__ out) {
  __shared__ __align__(16) f16 ZA[4096];
  __shared__ __align__(16) f16 HA[32768];
  __shared__ float redBuf[2][64];
  const int b = blockIdx.x;
  const int t = threadIdx.x;
  const int wave = t >> 6, lane = t & 63;
  const int sbase =
      wave * 4096 + (lane >> 4) * 32 + ((lane & 15) >> 3) * 128 + (lane & 7);
  const float* kb = koop + b * 4096;
#pragma unroll
  for (int i = 0; i < 8; i++) {
    int flat = t + 512 * i;
    ZA[aidx(flat & 63, flat >> 6)] = (f16)kb[flat];
  }
  __syncthreads();
  for (int net = 0; net < 2; net++) {
    const float* W1 = net ? tW1 : sW1;
    const float* W2 = net ? tW2 : sW2;
    const float* W3 = net ? tW3 : sW3;
    const float* W4 = net ? tW4 : sW4;
    const float* b1 = net ? tb1 : sb1;
    const float* b2 = net ? tb2 : sb2;
    const float* b3 = net ? tb3 : sb3;
    const float* b4 = net ? tb4 : sb4;
    mlp_layer_direct<2>(W1, b1, ZA, HA, wave, lane, sbase);
    mlp_layer_direct<16>(W2, b2, HA, HA, wave, lane, sbase);
    mlp_layer_direct<16>(W3, b3, HA, HA, wave, lane, sbase);
    int i = t >> 3, sub = t & 7;
    float p = 0.f;
#pragma unroll
    for (int qq = 0; qq < 8; qq++) {
      int k0 = sub * 64 + qq * 8;
      f16x8 hv = *(const f16x8*)&HA[aidx(i, k0)];
#pragma unroll
      for (int j = 0; j < 8; j++) p += (float)hv[j] * W4[(k0 + j) * 64 + i];
    }
    p += __shfl_down(p, 4, 8);
    p += __shfl_down(p, 2, 8);
    p += __shfl_down(p, 1, 8);
    if (sub == 0) redBuf[net][i] = p + b4[i];
    __syncthreads();
  }
  if (t < 64) {
    out[b * 64 + t] = (x[b * 64 + t] - redBuf[1][t]) * __expf(-redBuf[0][t]);
  }
}

extern "C" void kernel_launch(void* const* d_in, const int* in_sizes, int n_in,
                              void* d_out, int out_size, void* d_ws, size_t ws_size,
                              hipStream_t stream) {
  const float* x    = (const float*)d_in[0];
  const float* koop = (const float*)d_in[1];
  const float* sW1 = (const float*)d_in[2];  const float* sb1 = (const float*)d_in[3];
  const float* sW2 = (const float*)d_in[4];  const float* sb2 = (const float*)d_in[5];
  const float* sW3 = (const float*)d_in[6];  const float* sb3 = (const float*)d_in[7];
  const float* sW4 = (const float*)d_in[8];  const float* sb4 = (const float*)d_in[9];
  const float* tW1 = (const float*)d_in[10]; const float* tb1 = (const float*)d_in[11];
  const float* tW2 = (const float*)d_in[12]; const float* tb2 = (const float*)d_in[13];
  const float* tW3 = (const float*)d_in[14]; const float* tb3 = (const float*)d_in[15];
  const float* tW4 = (const float*)d_in[16]; const float* tb4 = (const float*)d_in[17];
  float* out = (float*)d_out;

  // Launch-invariant branch (ws_size constant across calls) -> graph-safe.
  // NEVER write past ws_size (R1 lesson).
  if (ws_size >= (size_t)WPACK_BYTES) {
    f16* wpack = (f16*)d_ws;
    pack_weights<<<4608, 256, 0, stream>>>(sW1, sW2, sW3, sW4, tW1, tW2, tW3, tW4,
                                           wpack);
    decoder_main<<<1024, 512, 0, stream>>>(x, koop, wpack,
                                           sb1, sb2, sb3, sb4,
                                           tb1, tb2, tb3, tb4, out);
  } else {
    decoder_direct<<<2048, 512, 0, stream>>>(
        x, koop, sW1, sW2, sW3, sW4, tW1, tW2, tW3, tW4,
        sb1, sb2, sb3, sb4, tb1, tb2, tb3, tb4, out);
  }
}